// Round 1
// baseline (1315.352 us; speedup 1.0000x reference)
//
#include <hip/hip_runtime.h>

// Problem constants: B=16, C=8, T=4096, L=512, K=32, SEG=128.
// out[b,c,k,l] = sum_s x[b,c,k*SEG+s,l] * w[s]
// Flat: block bid=(b*C+c)*K+k reads a CONTIGUOUS 256 KB segment:
//   x4[bid*SEG*L4 + s*L4 + t], writes out4[bid*L4 + t].
//
// v2: explicit two-buffer software pipeline so each wave never drains
// vmcnt to 0 — FMA on group A overlaps the 4 in-flight loads of group B.
// bufA/bufB are statically indexed (fully unrolled inner loops) so they
// stay in VGPRs, total ~56 VGPR -> full 32 waves/CU occupancy.

#define SEG 128
#define LDIM 512
#define L4 (LDIM / 4)   // 128 float4 per L-row

__global__ __launch_bounds__(128) void splitter_kernel(
    const float* __restrict__ x,
    const float* __restrict__ w,
    float* __restrict__ out)
{
    const int bid = blockIdx.x;       // 0 .. B*C*K-1 (4096)
    const int t   = threadIdx.x;      // 0 .. 127 : which float4 of the L row

    const float4* __restrict__ xb =
        reinterpret_cast<const float4*>(x) + (size_t)bid * (SEG * L4) + t;

    float4 bufA[4];
    float4 bufB[4];
    float4 acc = make_float4(0.f, 0.f, 0.f, 0.f);

    // Group = 4 consecutive s-rows. All indices compile-time after unroll.
#define LOADG(BUF, SB)                                                       \
    {                                                                        \
        _Pragma("unroll")                                                    \
        for (int u = 0; u < 4; ++u)                                          \
            BUF[u] = xb[((SB) + u) * L4];                                    \
    }

#define FMAG(BUF, SB)                                                        \
    {                                                                        \
        _Pragma("unroll")                                                    \
        for (int u = 0; u < 4; ++u) {                                        \
            const float ws = w[(SB) + u];  /* uniform -> s_load_dwordx4 */   \
            acc.x = fmaf(BUF[u].x, ws, acc.x);                               \
            acc.y = fmaf(BUF[u].y, ws, acc.y);                               \
            acc.z = fmaf(BUF[u].z, ws, acc.z);                               \
            acc.w = fmaf(BUF[u].w, ws, acc.w);                               \
        }                                                                    \
    }

    // Prologue: fill A with group 0.
    LOADG(bufA, 0);

    // Steady state: 15 iterations cover s = 0 .. 119 (A) / 4 .. 123 (B),
    // always issuing the next group's loads before consuming the current.
    int s = 0;
#pragma unroll 1
    for (int it = 0; it < 15; ++it, s += 8) {
        LOADG(bufB, s + 4);   // issue: outstanding = A(cur) + B(next)
        FMAG(bufA, s);        // waits vmcnt(4): A done, B still in flight
        LOADG(bufA, s + 8);   // issue next A
        FMAG(bufB, s + 4);    // waits vmcnt(4): B done, A in flight
    }
    // Epilogue: s == 120 here; A(120) already loaded.
    LOADG(bufB, 124);
    FMAG(bufA, 120);
    FMAG(bufB, 124);

#undef LOADG
#undef FMAG

    reinterpret_cast<float4*>(out)[(size_t)bid * L4 + t] = acc;
}

extern "C" void kernel_launch(void* const* d_in, const int* in_sizes, int n_in,
                              void* d_out, int out_size, void* d_ws, size_t ws_size,
                              hipStream_t stream)
{
    const float* x = (const float*)d_in[0];   // [B,C,T,L] fp32
    const float* w = (const float*)d_in[1];   // [SEG] fp32
    float* out     = (float*)d_out;           // [B,C,K,L] fp32

    const int nblocks = out_size / LDIM;      // B*C*K = 4096
    splitter_kernel<<<nblocks, 128, 0, stream>>>(x, w, out);
}

// Round 2
// 1315.245 us; speedup vs baseline: 1.0001x; 1.0001x over previous
//
#include <hip/hip_runtime.h>

// Problem constants: B=16, C=8, T=4096, L=512, K=32, SEG=128.
// out[b,c,k,l] = sum_s x[b,c,k*SEG+s,l] * w[s]
//
// v3: stream-count reduction. 512 blocks (was 4096); each block owns
// GSEG=8 consecutive k-segments and walks them strictly sequentially,
// giving one contiguous 2 MB stream per block (512 streams chip-wide
// instead of 4096) to restore DRAM row-buffer locality.
// Occupancy falls to ~1 wave/SIMD, so latency hiding is supplied by a
// 3-stage rotating pipeline (12 outstanding 1 KB loads per wave).

#define SEG  128
#define LDIM 512
#define L4   (LDIM / 4)   // 128 float4 per L-row
#define GSEG 8            // segments per block

__global__ __launch_bounds__(128) void splitter_kernel(
    const float* __restrict__ x,
    const float* __restrict__ w,
    float* __restrict__ out)
{
    const int bid = blockIdx.x;       // 0 .. 511
    const int t   = threadIdx.x;      // 0 .. 127

    const float4* __restrict__ xb =
        reinterpret_cast<const float4*>(x) + (size_t)bid * (GSEG * SEG * L4) + t;
    float4* __restrict__ ob =
        reinterpret_cast<float4*>(out) + (size_t)bid * (GSEG * L4) + t;

    float4 bufA[4];
    float4 bufB[4];
    float4 bufC[4];

    // Group = 4 consecutive s-rows; group id g covers s = 4g .. 4g+3.
#define LOADG(BUF, XS, G)                                                    \
    {                                                                        \
        _Pragma("unroll")                                                    \
        for (int u = 0; u < 4; ++u)                                          \
            BUF[u] = (XS)[((G) * 4 + u) * L4];                               \
    }

#define FMAG(BUF, G)                                                         \
    {                                                                        \
        _Pragma("unroll")                                                    \
        for (int u = 0; u < 4; ++u) {                                        \
            const float ws = w[(G) * 4 + u];  /* uniform scalar load */      \
            acc.x = fmaf(BUF[u].x, ws, acc.x);                               \
            acc.y = fmaf(BUF[u].y, ws, acc.y);                               \
            acc.z = fmaf(BUF[u].z, ws, acc.z);                               \
            acc.w = fmaf(BUF[u].w, ws, acc.w);                               \
        }                                                                    \
    }

#pragma unroll 1
    for (int g = 0; g < GSEG; ++g) {
        const float4* __restrict__ xs = xb + (size_t)g * (SEG * L4);
        float4 acc = make_float4(0.f, 0.f, 0.f, 0.f);

        // 32 groups of 4 rows. 3-stage rotation: 12 loads in flight,
        // each FMA group waits at vmcnt(8).
        LOADG(bufA, xs, 0);
        LOADG(bufB, xs, 1);

#pragma unroll 1
        for (int it = 0; it < 10; ++it) {
            const int g0 = 3 * it;
            LOADG(bufC, xs, g0 + 2);
            FMAG(bufA, g0 + 0);
            LOADG(bufA, xs, g0 + 3);
            FMAG(bufB, g0 + 1);
            LOADG(bufB, xs, g0 + 4);
            FMAG(bufC, g0 + 2);
        }
        // Consumed groups 0..29; groups 30 (A) and 31 (B) already loaded.
        FMAG(bufA, 30);
        FMAG(bufB, 31);

        ob[g * L4] = acc;
    }

#undef LOADG
#undef FMAG
}

extern "C" void kernel_launch(void* const* d_in, const int* in_sizes, int n_in,
                              void* d_out, int out_size, void* d_ws, size_t ws_size,
                              hipStream_t stream)
{
    const float* x = (const float*)d_in[0];   // [B,C,T,L] fp32
    const float* w = (const float*)d_in[1];   // [SEG] fp32
    float* out     = (float*)d_out;           // [B,C,K,L] fp32

    const int nblocks = (out_size / LDIM) / GSEG;  // 4096/8 = 512
    splitter_kernel<<<nblocks, 128, 0, stream>>>(x, w, out);
}